// Round 3
// baseline (176.061 us; speedup 1.0000x reference)
//
#include <hip/hip_runtime.h>

// BayesTensorRing via pair tables:
//   T01[i0*200+i1] = M0'[i0] · M1'[i1]              (row-major 16x16, 1 KB each)
//   T23[i2*200+i3] = (M2'[i2] · M3'[i3])^T          (transposed store)
//   out[s] = <T01[p_s], T23[q_s]>  (256-elem dot = trace of the 4-chain)
// Tables: 2 x 40000 x 256 fp32 = 81.92 MB in d_ws (L3-resident).
// Falls back to the direct per-sample chain if ws is too small.

constexpr int SPB = 64;
constexpr int BLK = 256;

#define DEV static __device__ __forceinline__

// ---------------- pair-table precompute ----------------
// Computes C[r][c] = sum_n (A[ia][r][n]*lamA[n]) * B[ib][n][c] * lamB[c]
// TRANS=false: thread t=(r*16+c) stores C at dst[pair*256 + r*16 + c]
// TRANS=true : thread t=(c*16+r) stores C at dst[pair*256 + c*16 + r]  (i.e. C^T)
template<bool TRANS>
__global__ __launch_bounds__(256)
void pair_table_kernel(const float* __restrict__ cA, const float* __restrict__ lA,
                       const float* __restrict__ cB, const float* __restrict__ lB,
                       float* __restrict__ dst)
{
    __shared__ __align__(16) float Bs[8 * 256];   // 8 raw B slices, 8 KB

    const int ia  = blockIdx.x / 25;
    const int ib0 = (blockIdx.x % 25) * 8;
    const int t   = threadIdx.x;

    // stage 8 consecutive B slices (2 float4s per thread, coalesced)
    {
        const float4* src = reinterpret_cast<const float4*>(cB + 256l * ib0);
        float4* d = reinterpret_cast<float4*>(Bs);
        d[t]       = src[t];
        d[t + 256] = src[t + 256];
    }

    int r, c;
    if constexpr (TRANS) { c = t >> 4; r = t & 15; }
    else                 { r = t >> 4; c = t & 15; }

    // A' row r (lamA folded), straight from global (L2-hot, broadcast across threads)
    float Ar[16];
    {
        const float4* a4 = reinterpret_cast<const float4*>(cA + 256l * ia + 16 * r);
#pragma unroll
        for (int q = 0; q < 4; ++q) {
            const float4 v = a4[q];
            const float4 L = reinterpret_cast<const float4*>(lA)[q];
            Ar[4*q+0] = v.x * L.x; Ar[4*q+1] = v.y * L.y;
            Ar[4*q+2] = v.z * L.z; Ar[4*q+3] = v.w * L.w;
        }
    }
    const float lamc = lB[c];

    __syncthreads();

#pragma unroll
    for (int i = 0; i < 8; ++i) {
        float acc = 0.f;
#pragma unroll
        for (int n = 0; n < 16; ++n)
            acc = fmaf(Ar[n], Bs[i * 256 + n * 16 + c], acc);
        dst[(ia * 200 + ib0 + i) * 256 + t] = acc * lamc;   // coalesced
    }
}

// ---------------- main: gather two table rows, 256-elem dot ----------------
__global__ __launch_bounds__(BLK)
void dot_kernel(const int* __restrict__ idx, const float* __restrict__ T01,
                const float* __restrict__ T23, float* __restrict__ out, int n)
{
    const int tid  = threadIdx.x;
    const int slot = tid >> 2;          // sample in block
    const int j    = tid & 3;           // lane in 4-lane group
    const int s    = blockIdx.x * SPB + slot;
    const int sc   = s < n ? s : n - 1;

    const int4 ix = *reinterpret_cast<const int4*>(idx + 4l * sc);
    const float4* a = reinterpret_cast<const float4*>(T01 + 256l * (ix.x * 200 + ix.y)) + j;
    const float4* b = reinterpret_cast<const float4*>(T23 + 256l * (ix.z * 200 + ix.w)) + j;

    float4 acc = make_float4(0.f, 0.f, 0.f, 0.f);
#pragma unroll
    for (int k = 0; k < 16; ++k) {      // lane j handles float4s j, 4+j, 8+j, ...
        const float4 va = a[4 * k];
        const float4 vb = b[4 * k];
        acc.x = fmaf(va.x, vb.x, acc.x);
        acc.y = fmaf(va.y, vb.y, acc.y);
        acc.z = fmaf(va.z, vb.z, acc.z);
        acc.w = fmaf(va.w, vb.w, acc.w);
    }
    float p = acc.x + acc.y + acc.z + acc.w;
    p += __shfl_xor(p, 1);
    p += __shfl_xor(p, 2);

    if (s < n && j == 0) out[s] = p;
}

// ---------------- fallback (R2 kernel, no workspace needed) ----------------
constexpr int MROW = 260;

DEV void mm16(const float (&a)[4][16], float (&b)[4][16], const float* __restrict__ m)
{
#pragma unroll
    for (int nn = 0; nn < 16; ++nn) {
        float mrow[16];
#pragma unroll
        for (int q = 0; q < 4; ++q) {
            const float4 v = *reinterpret_cast<const float4*>(m + 16 * nn + 4 * q);
            mrow[4*q+0] = v.x; mrow[4*q+1] = v.y; mrow[4*q+2] = v.z; mrow[4*q+3] = v.w;
        }
#pragma unroll
        for (int r = 0; r < 4; ++r) {
            const float av = a[r][nn];
            if (nn == 0) {
#pragma unroll
                for (int k = 0; k < 16; ++k) b[r][k] = av * mrow[k];
            } else {
#pragma unroll
                for (int k = 0; k < 16; ++k) b[r][k] = fmaf(av, mrow[k], b[r][k]);
            }
        }
    }
}

DEV void stage_slice(const float* __restrict__ core, const float* __restrict__ lam,
                     int index, int j, float* __restrict__ dst)
{
    const float4* src = reinterpret_cast<const float4*>(core + 256l * index);
    float4* d4 = reinterpret_cast<float4*>(dst);
    const float4 L = reinterpret_cast<const float4*>(lam)[j];
#pragma unroll
    for (int t = 0; t < 16; ++t) {
        float4 v = src[4 * t + j];
        v.x *= L.x; v.y *= L.y; v.z *= L.z; v.w *= L.w;
        d4[4 * t + j] = v;
    }
}

__global__ __launch_bounds__(BLK, 2)
void tr_trace_kernel(const int* __restrict__ idx,
                     const float* __restrict__ c0, const float* __restrict__ l0,
                     const float* __restrict__ c1, const float* __restrict__ l1,
                     const float* __restrict__ c2, const float* __restrict__ l2,
                     const float* __restrict__ c3, const float* __restrict__ l3,
                     float* __restrict__ out, int n)
{
    __shared__ __align__(16) float mbuf[SPB * MROW];

    const int tid  = threadIdx.x;
    const int slot = tid >> 2;
    const int j    = tid & 3;
    const int s    = blockIdx.x * SPB + slot;
    const int sc   = s < n ? s : n - 1;

    const int4 ix = *reinterpret_cast<const int4*>(idx + 4l * sc);
    float* myb = mbuf + slot * MROW;

    stage_slice(c1, l1, ix.y, j, myb);

    float a[4][16], b[4][16];
    {
        const float4* src = reinterpret_cast<const float4*>(c0 + 256l * ix.x) + 16 * j;
        float4 lv[4];
#pragma unroll
        for (int q = 0; q < 4; ++q) lv[q] = reinterpret_cast<const float4*>(l0)[q];
#pragma unroll
        for (int t = 0; t < 16; ++t) {
            float4 v = src[t];
            const float4 L = lv[t & 3];
            const int r = t >> 2, c = (t & 3) * 4;
            a[r][c+0] = v.x * L.x; a[r][c+1] = v.y * L.y;
            a[r][c+2] = v.z * L.z; a[r][c+3] = v.w * L.w;
        }
    }

    asm volatile("s_waitcnt lgkmcnt(0)" ::: "memory");
    mm16(a, b, myb);
    asm volatile("s_waitcnt lgkmcnt(0)" ::: "memory");
    stage_slice(c2, l2, ix.z, j, myb);
    asm volatile("s_waitcnt lgkmcnt(0)" ::: "memory");
    mm16(b, a, myb);

    float4 part = make_float4(0.f, 0.f, 0.f, 0.f);
    const float* base3 = c3 + 256l * ix.w + 4 * j;
#pragma unroll
    for (int nn = 0; nn < 16; ++nn) {
        const float4 v = *reinterpret_cast<const float4*>(base3 + 16 * nn);
        part.x = fmaf(a[0][nn], v.x, part.x);
        part.y = fmaf(a[1][nn], v.y, part.y);
        part.z = fmaf(a[2][nn], v.z, part.z);
        part.w = fmaf(a[3][nn], v.w, part.w);
    }
    const float4 L3 = reinterpret_cast<const float4*>(l3)[j];
    float p = part.x * L3.x + part.y * L3.y + part.z * L3.z + part.w * L3.w;

    p += __shfl_xor(p, 1);
    p += __shfl_xor(p, 2);

    if (s < n && j == 0) out[s] = p;
}

extern "C" void kernel_launch(void* const* d_in, const int* in_sizes, int n_in,
                              void* d_out, int out_size, void* d_ws, size_t ws_size,
                              hipStream_t stream)
{
    const int*   idx = (const int*)  d_in[0];
    const float* c0  = (const float*)d_in[1];
    const float* l0  = (const float*)d_in[2];
    const float* c1  = (const float*)d_in[3];
    const float* l1  = (const float*)d_in[4];
    const float* c2  = (const float*)d_in[5];
    const float* l2  = (const float*)d_in[6];
    const float* c3  = (const float*)d_in[7];
    const float* l3  = (const float*)d_in[8];
    float* out = (float*)d_out;

    const int n    = out_size;                 // 500000
    const int grid = (n + SPB - 1) / SPB;      // 7813 blocks

    const size_t need = 2ull * 40000 * 256 * sizeof(float);   // 81,920,000 B
    if (ws_size >= need) {
        float* T01 = (float*)d_ws;
        float* T23 = T01 + 40000l * 256;
        hipLaunchKernelGGL((pair_table_kernel<false>), dim3(200 * 25), dim3(256), 0, stream,
                           c0, l0, c1, l1, T01);
        hipLaunchKernelGGL((pair_table_kernel<true>),  dim3(200 * 25), dim3(256), 0, stream,
                           c2, l2, c3, l3, T23);
        hipLaunchKernelGGL(dot_kernel, dim3(grid), dim3(BLK), 0, stream,
                           idx, T01, T23, out, n);
    } else {
        hipLaunchKernelGGL(tr_trace_kernel, dim3(grid), dim3(BLK), 0, stream,
                           idx, c0, l0, c1, l1, c2, l2, c3, l3, out, n);
    }
}